// Round 2
// 419.042 us; speedup vs baseline: 1.0400x; 1.0400x over previous
//
#include <hip/hip_runtime.h>

#define HW     64
#define PLANE  4096   // 64*64
#define OW     62
#define NCH    512
#define NB     32
#define TOPK   256
#define LSTR   68     // padded LDS row stride (floats). Row stride 64 put every
                      // ds_read_b128 start-bank in {0,16} (8 banks served the whole
                      // wave = 4x conflict). Stride 68 -> start bank (4r+16s)%32,
                      // uniform 8 accesses/bank = provable minimum.

typedef float floatx4 __attribute__((ext_vector_type(4)));

// ---------------------------------------------------------------------------
// Kernel 1: per-(b,c)-plane curvature score = sum |3x3 valid conv response|.
// One block per plane. Stage plane to LDS (float4, padded stride), then each
// thread computes a 16-column run of ONE output row:
//   - 3 rows x 20 cols loaded as ds_read_b128 into fp32 registers
//   - stencil evaluated in FP32 (jax's conv is fp32; ranking risk is dominated
//     by jax's own fp32 sum error, not ours), accumulated in DOUBLE so our
//     score sits at the true value.
// Thread map: r = tid>>2 (0..61), seg = tid&3, cols seg*16..seg*16+15
// (seg 3 has only 14 valid outputs). tid 248..255 idle after staging.
// ---------------------------------------------------------------------------
__global__ __launch_bounds__(256) void score_kernel(const float* __restrict__ x,
                                                    double* __restrict__ p) {
    __shared__ float tile[64 * LSTR];   // 17408 B
    const int plane = blockIdx.x;
    const int tid = threadIdx.x;

    // ---- stage plane to LDS, coalesced float4, padded rows ----
    const float4* src4 = (const float4*)(x + (size_t)plane * PLANE);
    #pragma unroll
    for (int i = 0; i < 4; ++i) {
        const int g = tid + 256 * i;     // float4 index 0..1023
        const int row = g >> 4;          // 16 float4 per 64-float row
        const int c4 = g & 15;
        *(float4*)(tile + row * LSTR + c4 * 4) = src4[g];
    }
    __syncthreads();

    double acc = 0.0;
    if (tid < 248) {
        const int r = tid >> 2;      // output row 0..61
        const int s = tid & 3;       // column segment
        const int c0 = s * 16;       // first output col of this segment

        // ---- vector-load 3 input rows x 20 cols into registers ----
        float f0[20], f1[20], f2[20];
        const float* row0 = tile + r * LSTR + c0;
        const float* row1 = row0 + LSTR;
        const float* row2 = row0 + 2 * LSTR;
        #pragma unroll
        for (int v = 0; v < 4; ++v) {
            *(float4*)(f0 + 4 * v) = *(const float4*)(row0 + 4 * v);
            *(float4*)(f1 + 4 * v) = *(const float4*)(row1 + 4 * v);
            *(float4*)(f2 + 4 * v) = *(const float4*)(row2 + 4 * v);
        }
        if (s < 3) {
            *(float4*)(f0 + 16) = *(const float4*)(row0 + 16);
            *(float4*)(f1 + 16) = *(const float4*)(row1 + 16);
            *(float4*)(f2 + 16) = *(const float4*)(row2 + 16);
        } else {
            #pragma unroll
            for (int j = 16; j < 20; ++j) { f0[j] = 0.f; f1[j] = 0.f; f2[j] = 0.f; }
        }

        const int nvalid = (s == 3) ? 14 : 16;   // seg 3 covers cols 48..61
        const float C5 = 0.3125f;    // 5/16, exact
        const float CM = -0.0625f;   // -1/16, exact

        #pragma unroll
        for (int u = 0; u < 16; ++u) {
            // vertical pair sums, grouped identically across u for CSE
            float a0 = f0[u]     + f2[u];
            float a1 = f0[u + 1] + f2[u + 1];
            float a2 = f0[u + 2] + f2[u + 2];
            float plus = a1 + f1[u] + f1[u + 2];
            float diag = a0 + a2;
            float resp = fmaf(C5, plus, fmaf(CM, diag, -f1[u + 1]));
            acc += (u < nvalid) ? (double)fabsf(resp) : 0.0;
        }
    }

    // ---- block reduce: 64-lane shuffle, then cross-wave LDS ----
    #pragma unroll
    for (int off = 32; off > 0; off >>= 1)
        acc += __shfl_down(acc, off, 64);

    __shared__ double wsum[4];
    const int wave = tid >> 6;
    if ((tid & 63) == 0) wsum[wave] = acc;
    __syncthreads();
    if (tid == 0)
        p[plane] = wsum[0] + wsum[1] + wsum[2] + wsum[3];
}

// ---------------------------------------------------------------------------
// Kernel 2: exact top-k by rank. One block per batch, 512 threads.
// rank[c] = #{j : p[j] > p[c]  or  (p[j]==p[c] and j<c)}  -- matches
// jax.lax.top_k ordering (descending, ties -> lower index first).
// ---------------------------------------------------------------------------
__global__ __launch_bounds__(512) void topk_kernel(const double* __restrict__ p,
                                                   int* __restrict__ idx) {
    __shared__ double sp[NCH];
    const int b = blockIdx.x;
    const int c = threadIdx.x;
    sp[c] = p[(size_t)b * NCH + c];
    __syncthreads();

    const double mine = sp[c];
    int rank = 0;
    for (int j = 0; j < NCH; ++j) {
        const double v = sp[j];
        rank += (v > mine) || (v == mine && j < c) ? 1 : 0;
    }
    if (rank < TOPK)
        idx[(size_t)b * TOPK + rank] = c;
}

// ---------------------------------------------------------------------------
// Kernel 3: gather selected channel planes. One block per (b, rank).
// REVERSED block order: score just streamed all 256 MiB of x through the
// 256 MiB L3, so the TAIL of x (high b) is resident — gather batch 31 first
// to hit L3 instead of HBM. Output stores are non-temporal (never re-read)
// so they don't evict x from L3 while we still need it.
// ---------------------------------------------------------------------------
__global__ __launch_bounds__(256) void gather_kernel(const float* __restrict__ x,
                                                     const int* __restrict__ idx,
                                                     float* __restrict__ out) {
    const int bj = NB * TOPK - 1 - blockIdx.x;   // batch 31 first
    const int b = bj >> 8;                       // TOPK == 256
    const int ch = idx[bj];
    const floatx4* src = (const floatx4*)(x + ((size_t)b * NCH + ch) * PLANE);
    floatx4* dst = (floatx4*)(out + (size_t)bj * PLANE);
    const int tid = threadIdx.x;
    #pragma unroll
    for (int i = 0; i < 4; ++i) {
        floatx4 v = src[tid + 256 * i];
        __builtin_nontemporal_store(v, dst + tid + 256 * i);
    }
}

extern "C" void kernel_launch(void* const* d_in, const int* in_sizes, int n_in,
                              void* d_out, int out_size, void* d_ws, size_t ws_size,
                              hipStream_t stream) {
    const float* x = (const float*)d_in[0];
    float* out = (float*)d_out;

    // workspace layout: p (16384 doubles = 128 KB) | idx (8192 ints = 32 KB)
    double* p = (double*)d_ws;
    int* idx = (int*)((char*)d_ws + (size_t)NB * NCH * sizeof(double));

    score_kernel<<<NB * NCH, 256, 0, stream>>>(x, p);
    topk_kernel<<<NB, NCH, 0, stream>>>(p, idx);
    gather_kernel<<<NB * TOPK, 256, 0, stream>>>(x, idx, out);
}